// Round 3
// baseline (150.475 us; speedup 1.0000x reference)
//
#include <hip/hip_runtime.h>
#include <math.h>
#include <stdint.h>

// Problem constants: B,H,K,L,V = 4096,1024,10,64,80
constexpr int Bn = 4096;
constexpr int Hn = 1024;
constexpr int Kn = 10;
constexpr int Ln = 64;
constexpr int Vn = 80;
constexpr int NJ = 3 * Kn;   // 30
constexpr int R  = 8;        // batch rows per block
constexpr int NT = 256;
// grid = 512 blocks -> exactly 2 blocks/CU, both resident (LDS 51.4 KB/block).

// async global->LDS, 16B/lane, wave-uniform LDS base (linear copy)
typedef const __attribute__((address_space(1))) uint32_t glb_u32;
typedef __attribute__((address_space(3))) uint32_t lds_u32;
__device__ __forceinline__ void gload_lds16(const void* g, void* l) {
    __builtin_amdgcn_global_load_lds((glb_u32*)g, (lds_u32*)l, 16, 0, 0);
}
#define VMCNT(n) asm volatile("s_waitcnt vmcnt(" #n ")" ::: "memory")
#define LGKM0()  asm volatile("s_waitcnt lgkmcnt(0)" ::: "memory")
#define BAR()    __builtin_amdgcn_s_barrier()
#define SCHED()  __builtin_amdgcn_sched_barrier(0)

__global__ __launch_bounds__(NT) void window_fused(
    const float* __restrict__ x,      // [B,H]
    const float* __restrict__ chars,  // [B,L,V]
    const float* __restrict__ W,      // [H,3K]
    const float* __restrict__ bias,   // [3K]
    float* __restrict__ out)          // [B,V]
{
    // 2 x 20 KB chars double-buffer; also stages x (32 KB) in Phase A and
    // the einsum cross-thread partials (30.7 KB) in the epilogue.
    __shared__ float4 buf[2][Ln * Vn / 4];   // 40960 B
    __shared__ float  red[R * 256];          // 8192 B GEMM partials
    __shared__ float  abk[R * NJ];           // 960 B
    __shared__ float  phi_s[R * Ln];         // 2048 B

    const int t    = threadIdx.x;
    const int lane = t & 63;
    const int w    = t >> 6;                 // wave 0..3
    const int row0 = blockIdx.x * R;

    // ================= Phase A: GEMM -> abk -> phi (NO chars in flight) ======
    // x rows are contiguous: 8 rows x 4 KB = 32 KB, staged linearly across buf.
    {
        const char* xg = (const char*)(x + (size_t)row0 * Hn);
        char*       bl = (char*)buf;
#pragma unroll
        for (int i = 0; i < 8; ++i) {               // 32 chunks of 1 KB, 8/wave
            const int off = (w * 8 + i) * 1024;
            gload_lds16(xg + off + lane * 16, bl + off);
        }
    }
    VMCNT(0); BAR(); SCHED();

    // GEMM partials: red[r][g*32+j] = sum_{h in g's 128-range} x[r][h]*W[h][j]
    {
        const float4* xs4 = (const float4*)buf;     // row stride 256 float4
        const int j = t & 31;
        const int g = t >> 5;
        float acc[R];
#pragma unroll
        for (int r = 0; r < R; ++r) acc[r] = 0.f;
        if (j < NJ) {
            const float* Wp = W + j;
            const int h0 = g * 128;
#pragma unroll 4
            for (int ii = 0; ii < 128; ii += 4) {
                const int h  = h0 + ii;
                const int h4 = h >> 2;
                float w0 = Wp[(h + 0) * NJ];
                float w1 = Wp[(h + 1) * NJ];
                float w2 = Wp[(h + 2) * NJ];
                float w3 = Wp[(h + 3) * NJ];
#pragma unroll
                for (int r = 0; r < R; ++r) {
                    float4 v = xs4[r * 256 + h4];   // LDS broadcast across j
                    acc[r] += w0 * v.x + w1 * v.y + w2 * v.z + w3 * v.w;
                }
            }
        }
#pragma unroll
        for (int r = 0; r < R; ++r) red[r * 256 + g * 32 + j] = acc[r];
    }
    LGKM0(); BAR(); SCHED();

    // Reduce + bias + exp. bias is a global load: consumed BEFORE chars issue.
    if (t < R * NJ) {  // 240 threads
        const int r = t / NJ, jj = t % NJ;
        float s = bias[jj];
#pragma unroll
        for (int gg = 0; gg < 8; ++gg) s += red[r * 256 + gg * 32 + jj];
        abk[r * NJ + jj] = __expf(s);
    }
    LGKM0(); BAR(); SCHED();

    // ====== Start chars stream NOW (vmcnt queue is clean), phi overlaps ======
    const char* cg = (const char*)(chars + (size_t)row0 * Ln * Vn);
    VMCNT(0);  // clean base so counted waits below are exact
#define ISSUE(gi, bsel)                                                     \
    {                                                                       \
        const char* src = cg + (gi) * 20480;                                \
        char*       dst = (char*)(buf[(bsel)]);                             \
        _Pragma("unroll")                                                   \
        for (int c2 = 0; c2 < 5; ++c2) {       /* 20 chunks, 5/wave */      \
            const int off = (w * 5 + c2) * 1024;                            \
            gload_lds16(src + off + lane * 16, dst + off);                  \
        }                                                                   \
    }
    ISSUE(0, 0);
    ISSUE(1, 1);

    // phi[r][l] = sum_k alpha*exp(-beta*(kappa-l)^2)  (VALU, hides under stream)
    {
        const int l = t & 63;
        const float lf = (float)l;
#pragma unroll
        for (int rr = 0; rr < 2; ++rr) {
            const int r = (t >> 6) + rr * 4;
            const float* ab = abk + r * NJ;
            float ph = 0.f;
#pragma unroll
            for (int k = 0; k < Kn; ++k) {
                float a  = ab[k];
                float bt = ab[Kn + k];
                float kp = ab[2 * Kn + k];
                float d  = kp - lf;
                ph += a * __expf(-bt * d * d);
            }
            phi_s[r * Ln + l] = ph;
        }
    }
    LGKM0(); BAR(); SCHED();  // phi_s visible; chars g0 NOT yet awaited

    // ================= Phase B: counted-vmcnt double-buffered einsum =========
    const int v4 = t % 20;
    const int lg = t / 20;    // 0..11 for t<240
    float4 eacc[R];
#pragma unroll
    for (int i = 0; i < R; ++i) eacc[i] = make_float4(0.f, 0.f, 0.f, 0.f);

#pragma unroll
    for (int i = 0; i < R; ++i) {
        if (i < R - 1) { VMCNT(5); } else { VMCNT(0); }  // never drain mid-loop
        BAR(); SCHED();
        if (t < 240) {
            const float4* cs = (const float4*)(buf[i & 1]);
            float4 a = eacc[i];                          // static index (unrolled)
            for (int l = lg; l < Ln; l += 12) {
                float4 c = cs[l * 20 + v4];              // conflict-light ds_read_b128
                float  p = phi_s[i * Ln + l];
                a.x += p * c.x; a.y += p * c.y; a.z += p * c.z; a.w += p * c.w;
            }
            eacc[i] = a;
        }
        LGKM0(); BAR(); SCHED();                         // all waves done reading
        if (i + 2 < R) ISSUE(i + 2, i & 1);              // refill the buffer just freed
    }

    // ================= Epilogue: cross-thread reduce via dead buffers ========
    float4* cpart = (float4*)buf;                        // 1920 float4 = 30.7 KB
    if (t < 240) {
#pragma unroll
        for (int i = 0; i < R; ++i) cpart[i * 240 + t] = eacc[i];
    }
    LGKM0(); BAR(); SCHED();

    if (t < R * 20) {  // 160 threads: one float4 of out per thread
        const int r  = t / 20;
        const int vv = t % 20;
        float4 s = make_float4(0.f, 0.f, 0.f, 0.f);
#pragma unroll
        for (int gg = 0; gg < 12; ++gg) {
            float4 p = cpart[r * 240 + gg * 20 + vv];
            s.x += p.x; s.y += p.y; s.z += p.z; s.w += p.w;
        }
        ((float4*)out)[(size_t)(row0 + r) * 20 + vv] = s;
    }
}

extern "C" void kernel_launch(void* const* d_in, const int* in_sizes, int n_in,
                              void* d_out, int out_size, void* d_ws, size_t ws_size,
                              hipStream_t stream) {
    const float* x     = (const float*)d_in[0];
    const float* chars = (const float*)d_in[1];
    const float* W     = (const float*)d_in[2];
    const float* bias  = (const float*)d_in[3];
    float* out = (float*)d_out;

    window_fused<<<Bn / R, NT, 0, stream>>>(x, chars, W, bias, out);
}

// Round 4
// 146.926 us; speedup vs baseline: 1.0242x; 1.0242x over previous
//
#include <hip/hip_runtime.h>
#include <math.h>

// Problem constants: B,H,K,L,V = 4096,1024,10,64,80
constexpr int Bn = 4096;
constexpr int Hn = 1024;
constexpr int Kn = 10;
constexpr int Ln = 64;
constexpr int Vn = 80;
constexpr int NJ = 3 * Kn;   // 30
constexpr int R1 = 4;        // rows/block, phi kernel
constexpr int NT1 = 256;
constexpr int RW = 8;        // rows/block, einsum kernel
constexpr int NT2 = 320;     // 8 rows * 20 float4-cols * 2 halves, zero idle lanes

// ---------------------------------------------------------------------------
// K1: phi[b][l] = sum_k alpha*exp(-beta*(kappa-l)^2).  Round-0-proven GEMM
// structure. grid 1024, 4 blocks/CU (LDS ~20.5 KB), 16 waves/CU.
// ---------------------------------------------------------------------------
__global__ __launch_bounds__(NT1) void phi_kernel(
    const float* __restrict__ x,      // [B,H]
    const float* __restrict__ W,      // [H,3K]
    const float* __restrict__ bias,   // [3K]
    float* __restrict__ phi)          // [B,L] (workspace)
{
    __shared__ float xs[R1 * Hn];     // 16 KB
    __shared__ float part[R1 * 256];  // 4 KB
    __shared__ float abk[R1 * NJ];    // 480 B

    const int t    = threadIdx.x;
    const int row0 = blockIdx.x * R1;

    const float4* x4  = (const float4*)x;
    float4*       xs4 = (float4*)xs;
#pragma unroll
    for (int r = 0; r < R1; ++r)
        xs4[r * (Hn / 4) + t] = x4[(size_t)(row0 + r) * (Hn / 4) + t];
    __syncthreads();

    // GEMM partials: j = t&31 (j<30 active), g = t>>5 covers 128 h each
    const int j = t & 31;
    const int g = t >> 5;
    float acc0 = 0.f, acc1 = 0.f, acc2 = 0.f, acc3 = 0.f;
    if (j < NJ) {
        const float* Wp = W + j;
        const int h0 = g * 128;
#pragma unroll 4
        for (int ii = 0; ii < 128; ii += 4) {
            const int h  = h0 + ii;
            const int h4 = h >> 2;
            float4 xa = xs4[0 * (Hn / 4) + h4];
            float4 xb = xs4[1 * (Hn / 4) + h4];
            float4 xc = xs4[2 * (Hn / 4) + h4];
            float4 xd = xs4[3 * (Hn / 4) + h4];
            float w0 = Wp[(h + 0) * NJ];
            float w1 = Wp[(h + 1) * NJ];
            float w2 = Wp[(h + 2) * NJ];
            float w3 = Wp[(h + 3) * NJ];
            acc0 += w0 * xa.x + w1 * xa.y + w2 * xa.z + w3 * xa.w;
            acc1 += w0 * xb.x + w1 * xb.y + w2 * xb.z + w3 * xb.w;
            acc2 += w0 * xc.x + w1 * xc.y + w2 * xc.z + w3 * xc.w;
            acc3 += w0 * xd.x + w1 * xd.y + w2 * xd.z + w3 * xd.w;
        }
    }
    part[0 * 256 + g * 32 + j] = acc0;
    part[1 * 256 + g * 32 + j] = acc1;
    part[2 * 256 + g * 32 + j] = acc2;
    part[3 * 256 + g * 32 + j] = acc3;
    __syncthreads();

    if (t < R1 * NJ) {  // 120 threads
        const int r = t / NJ, jj = t % NJ;
        float s = bias[jj];
#pragma unroll
        for (int gg = 0; gg < 8; ++gg) s += part[r * 256 + gg * 32 + jj];
        abk[r * NJ + jj] = __expf(s);
    }
    __syncthreads();

    // phi: 256 threads -> 256 consecutive floats of this block's phi rows
    {
        const int r = t >> 6, l = t & 63;
        const float lf = (float)l;
        const float* ab = abk + r * NJ;
        float ph = 0.f;
#pragma unroll
        for (int k = 0; k < Kn; ++k) {
            float a  = ab[k];
            float bt = ab[Kn + k];
            float kp = ab[2 * Kn + k];
            float d  = kp - lf;
            ph += a * __expf(-bt * d * d);
        }
        phi[(size_t)row0 * Ln + t] = ph;   // coalesced (t == r*64+l)
    }
}

// ---------------------------------------------------------------------------
// K2: out[b][v] = sum_l phi[b][l] * chars[b][l][v].
// No chars LDS staging (zero reuse). One (row, float4-col, half) per thread:
// 32 fully-unrolled independent float4 loads -> deep ILP per thread.
// grid 512, 320 thr (5 waves), 2 blocks/CU, ~50 KB in flight per CU.
// ---------------------------------------------------------------------------
__global__ __launch_bounds__(NT2) void einsum_kernel(
    const float* __restrict__ phi,    // [B,L]
    const float* __restrict__ chars,  // [B,L,V]
    float* __restrict__ out)          // [B,V]
{
    __shared__ float phi_s[RW * Ln];  // 2 KB

    const int t    = threadIdx.x;
    const int row0 = blockIdx.x * RW;

    // stage phi rows: 512 floats = 128 float4
    if (t < 128)
        ((float4*)phi_s)[t] = ((const float4*)(phi + (size_t)row0 * Ln))[t];
    __syncthreads();

    const int r    = t / 40;          // 0..7  (never straddles a lane pair)
    const int q    = t % 40;
    const int v4   = q >> 1;          // 0..19 float4 column
    const int half = q & 1;           // lanes 2k/2k+1 share (r,v4)

    const float4* cb = (const float4*)chars
                     + (size_t)(row0 + r) * (Ln * Vn / 4)   // row panel (1280)
                     + (size_t)(half * 32) * (Vn / 4)       // l-half offset
                     + v4;
    const float* ph = phi_s + r * Ln + half * 32;

    float4 acc = make_float4(0.f, 0.f, 0.f, 0.f);
#pragma unroll
    for (int i = 0; i < 32; ++i) {    // 32 independent global float4 loads
        float4 c = cb[i * (Vn / 4)];
        float  p = ph[i];
        acc.x += p * c.x; acc.y += p * c.y; acc.z += p * c.z; acc.w += p * c.w;
    }

    // combine the two halves: adjacent lanes, one xor-shuffle
    acc.x += __shfl_xor(acc.x, 1);
    acc.y += __shfl_xor(acc.y, 1);
    acc.z += __shfl_xor(acc.z, 1);
    acc.w += __shfl_xor(acc.w, 1);

    if (half == 0)
        ((float4*)out)[(size_t)(row0 + r) * (Vn / 4) + v4] = acc;
}

// ---------------------------------------------------------------------------
// Fused fallback (round-0 proven kernel) — only if ws too small.
// ---------------------------------------------------------------------------
__global__ __launch_bounds__(NT1) void window_kernel(
    const float* __restrict__ x,
    const float* __restrict__ chars,
    const float* __restrict__ W,
    const float* __restrict__ bias,
    float* __restrict__ out)
{
    __shared__ float  xs[R1 * Hn];
    __shared__ float  part[R1 * 256];
    __shared__ float  abk[R1 * NJ];
    __shared__ float  phi_s[R1 * Ln];
    __shared__ float4 cpart[R1 * 12 * 20];

    const int t    = threadIdx.x;
    const int row0 = blockIdx.x * R1;

    const float4* x4  = (const float4*)x;
    float4*       xs4 = (float4*)xs;
#pragma unroll
    for (int r = 0; r < R1; ++r)
        xs4[r * (Hn / 4) + t] = x4[(size_t)(row0 + r) * (Hn / 4) + t];
    __syncthreads();

    const int j = t & 31;
    const int g = t >> 5;
    float acc0 = 0.f, acc1 = 0.f, acc2 = 0.f, acc3 = 0.f;
    if (j < NJ) {
        const float* Wp = W + j;
        const int h0 = g * 128;
#pragma unroll 4
        for (int ii = 0; ii < 128; ii += 4) {
            const int h  = h0 + ii;
            const int h4 = h >> 2;
            float4 xa = xs4[0 * (Hn / 4) + h4];
            float4 xb = xs4[1 * (Hn / 4) + h4];
            float4 xc = xs4[2 * (Hn / 4) + h4];
            float4 xd = xs4[3 * (Hn / 4) + h4];
            float w0 = Wp[(h + 0) * NJ];
            float w1 = Wp[(h + 1) * NJ];
            float w2 = Wp[(h + 2) * NJ];
            float w3 = Wp[(h + 3) * NJ];
            acc0 += w0 * xa.x + w1 * xa.y + w2 * xa.z + w3 * xa.w;
            acc1 += w0 * xb.x + w1 * xb.y + w2 * xb.z + w3 * xb.w;
            acc2 += w0 * xc.x + w1 * xc.y + w2 * xc.z + w3 * xc.w;
            acc3 += w0 * xd.x + w1 * xd.y + w2 * xd.z + w3 * xd.w;
        }
    }
    part[0 * 256 + g * 32 + j] = acc0;
    part[1 * 256 + g * 32 + j] = acc1;
    part[2 * 256 + g * 32 + j] = acc2;
    part[3 * 256 + g * 32 + j] = acc3;
    __syncthreads();

    if (t < R1 * NJ) {
        const int r = t / NJ, jj = t % NJ;
        float s = bias[jj];
#pragma unroll
        for (int gg = 0; gg < 8; ++gg) s += part[r * 256 + gg * 32 + jj];
        abk[r * NJ + jj] = __expf(s);
    }
    __syncthreads();

    {
        const int r = t >> 6, l = t & 63;
        const float lf = (float)l;
        const float* ab = abk + r * NJ;
        float ph = 0.f;
#pragma unroll
        for (int k = 0; k < Kn; ++k) {
            float a  = ab[k];
            float bt = ab[Kn + k];
            float kp = ab[2 * Kn + k];
            float d  = kp - lf;
            ph += a * __expf(-bt * d * d);
        }
        phi_s[r * Ln + l] = ph;
    }
    __syncthreads();

    const float4* c4 = (const float4*)chars;
    if (t < 240) {
        const int v4  = t % 20;
        const int g12 = t / 20;
        float4 s0 = make_float4(0.f, 0.f, 0.f, 0.f);
        float4 s1 = s0, s2 = s0, s3 = s0;
        for (int l = g12; l < Ln; l += 12) {
            const int off = l * 20 + v4;
            float4 cA = c4[(size_t)(row0 + 0) * 1280 + off];
            float4 cB = c4[(size_t)(row0 + 1) * 1280 + off];
            float4 cC = c4[(size_t)(row0 + 2) * 1280 + off];
            float4 cD = c4[(size_t)(row0 + 3) * 1280 + off];
            float p0 = phi_s[0 * Ln + l];
            float p1 = phi_s[1 * Ln + l];
            float p2 = phi_s[2 * Ln + l];
            float p3 = phi_s[3 * Ln + l];
            s0.x += p0 * cA.x; s0.y += p0 * cA.y; s0.z += p0 * cA.z; s0.w += p0 * cA.w;
            s1.x += p1 * cB.x; s1.y += p1 * cB.y; s1.z += p1 * cB.z; s1.w += p1 * cB.w;
            s2.x += p2 * cC.x; s2.y += p2 * cC.y; s2.z += p2 * cC.z; s2.w += p2 * cC.w;
            s3.x += p3 * cD.x; s3.y += p3 * cD.y; s3.z += p3 * cD.z; s3.w += p3 * cD.w;
        }
        cpart[(0 * 12 + g12) * 20 + v4] = s0;
        cpart[(1 * 12 + g12) * 20 + v4] = s1;
        cpart[(2 * 12 + g12) * 20 + v4] = s2;
        cpart[(3 * 12 + g12) * 20 + v4] = s3;
    }
    __syncthreads();

    if (t < 80) {
        const int r  = t / 20;
        const int vv = t % 20;
        float4 s = make_float4(0.f, 0.f, 0.f, 0.f);
#pragma unroll
        for (int gg = 0; gg < 12; ++gg) {
            float4 p = cpart[(r * 12 + gg) * 20 + vv];
            s.x += p.x; s.y += p.y; s.z += p.z; s.w += p.w;
        }
        ((float4*)out)[(size_t)(row0 + r) * 20 + vv] = s;
    }
}

extern "C" void kernel_launch(void* const* d_in, const int* in_sizes, int n_in,
                              void* d_out, int out_size, void* d_ws, size_t ws_size,
                              hipStream_t stream) {
    const float* x     = (const float*)d_in[0];
    const float* chars = (const float*)d_in[1];
    const float* W     = (const float*)d_in[2];
    const float* bias  = (const float*)d_in[3];
    float* out = (float*)d_out;

    const size_t phi_bytes = (size_t)Bn * Ln * sizeof(float);  // 1 MB
    if (d_ws != nullptr && ws_size >= phi_bytes) {
        float* phi = (float*)d_ws;
        phi_kernel<<<Bn / R1, NT1, 0, stream>>>(x, W, bias, phi);
        einsum_kernel<<<Bn / RW, NT2, 0, stream>>>(phi, chars, out);
    } else {
        window_kernel<<<Bn / R1, NT1, 0, stream>>>(x, chars, W, bias, out);
    }
}